// Round 11
// baseline (324.952 us; speedup 1.0000x reference)
//
#include <hip/hip_runtime.h>
#include <hip/hip_bf16.h>

// GraphConv: out = segment_sum(edge_val * X[edge_col], edge_row) @ W + bias
// Pipeline: prep(bf16 X,W)+bucket-count(+table) | bucket-scan | partition
// (u64{row_low|col|val} into 1563 64-row buckets) | FUSED per-bucket
// counting sort by (row, col-group) + column-phase-sweep aggregation
// (group-outer loop: whole GPU gathers from one 2.1MB column slice at a
// time -> L2-resident) | MFMA GEMM (+bias)

#define N_NODES 100000
#define N_EDGES 3200000
#define DIM 128
#define RB 16
#define RPB 64                                   // rows per bucket
#define NBKT ((N_NODES + RPB - 1) / RPB)         // 1563
#define CHUNK 8192
#define NCHK ((N_EDGES + CHUNK - 1) / CHUNK)     // 391
#define NGRP 16                                  // key slots (13 used: col>>13)
#define CAP3 2688                                // bucket cap (mean 2048, +14 sigma)

typedef __attribute__((ext_vector_type(8))) short bf16x8;
typedef __attribute__((ext_vector_type(4))) float f32x4;
typedef unsigned long long u64;
typedef unsigned int u32;

__device__ inline ushort bf16rne(float f) {
  uint32_t u = __float_as_uint(f);
  u += 0x7fffu + ((u >> 16) & 1u);
  return (ushort)(u >> 16);
}
__device__ inline float lofl(u32 u) { return __uint_as_float(u << 16); }
__device__ inline float hifl(u32 u) { return __uint_as_float(u & 0xffff0000u); }

// ------- fused: prep (blocks 0..1023) + bucket count (blocks 1024..) -------
__global__ __launch_bounds__(256) void prep_count_kernel(
    const float* __restrict__ X, const float* __restrict__ W,
    ushort* __restrict__ Xh, ushort* __restrict__ Wh,
    const int* __restrict__ erow, int* __restrict__ bcnt,
    int* __restrict__ table) {
  __shared__ int cnt[NBKT];
  if (blockIdx.x < 1024) {
    const size_t nx4 = (size_t)N_NODES * DIM / 4;
    const size_t nw4 = (size_t)DIM * DIM / 4;
    for (size_t i = (size_t)blockIdx.x * blockDim.x + threadIdx.x;
         i < nx4 + nw4; i += (size_t)1024 * blockDim.x) {
      const float4 f = (i < nx4) ? ((const float4*)X)[i] : ((const float4*)W)[i - nx4];
      ushort4 h;
      h.x = bf16rne(f.x); h.y = bf16rne(f.y); h.z = bf16rne(f.z); h.w = bf16rne(f.w);
      if (i < nx4) ((ushort4*)Xh)[i] = h;
      else         ((ushort4*)Wh)[i - nx4] = h;
    }
  } else {
    const int cb = blockIdx.x - 1024;
    for (int b = threadIdx.x; b < NBKT; b += 256) cnt[b] = 0;
    __syncthreads();
    const int e0 = cb * CHUNK;
    #pragma unroll
    for (int it = 0; it < CHUNK / 256; ++it) {
      const int e = e0 + it * 256 + threadIdx.x;
      if (e < N_EDGES) atomicAdd(&cnt[erow[e] >> 6], 1);
    }
    __syncthreads();
    for (int b = threadIdx.x; b < NBKT; b += 256) {
      const int c = cnt[b];
      table[(size_t)cb * NBKT + b] = c;
      if (c) atomicAdd(&bcnt[b], c);
    }
  }
}

// ------- exclusive scan over 1563 bucket counts (2 elems/thread) -----------
__global__ __launch_bounds__(1024) void bscan_kernel(int* __restrict__ bcur,
                                                     int* __restrict__ bbase) {
  __shared__ int wsum[32];
  const int t = threadIdx.x, lane = t & 63, wid = t >> 6;   // wid 0..15
  int v0 = (t < NBKT) ? bcur[t] : 0;
  int v1 = (t + 1024 < NBKT) ? bcur[t + 1024] : 0;
  int i0 = v0, i1 = v1;
  #pragma unroll
  for (int off = 1; off < 64; off <<= 1) {
    int n0 = __shfl_up(i0, off, 64);
    int n1 = __shfl_up(i1, off, 64);
    if (lane >= off) { i0 += n0; i1 += n1; }
  }
  if (lane == 63) { wsum[wid] = i0; wsum[16 + wid] = i1; }
  __syncthreads();
  if (t == 0) {
    int s = 0;
    #pragma unroll
    for (int k = 0; k < 32; ++k) { int x = wsum[k]; wsum[k] = s; s += x; }
    bbase[NBKT] = s;
  }
  __syncthreads();
  const int e0 = wsum[wid] + i0 - v0;
  const int e1 = wsum[16 + wid] + i1 - v1;
  if (t < NBKT) { bbase[t] = e0; bcur[t] = e0; }
  if (t + 1024 < NBKT) { bbase[t + 1024] = e1; bcur[t + 1024] = e1; }
}

// ------- partition edges into buckets (u64 = row_low | col | val) ----------
__global__ __launch_bounds__(256) void partition_kernel(
    const int* __restrict__ erow, const int* __restrict__ ecol,
    const float* __restrict__ eval, const int* __restrict__ table,
    int* __restrict__ bcur, u64* __restrict__ p64) {
  __shared__ int cnt[NBKT];
  const int e0 = blockIdx.x * CHUNK;
  for (int b = threadIdx.x; b < NBKT; b += 256) {
    const int c = table[(size_t)blockIdx.x * NBKT + b];
    cnt[b] = c ? atomicAdd(&bcur[b], c) : 0;
  }
  __syncthreads();
  #pragma unroll
  for (int it = 0; it < CHUNK / 256; ++it) {
    const int e = e0 + it * 256 + threadIdx.x;
    if (e < N_EDGES) {
      const int r = erow[e];
      const u32 lo = ((u32)ecol[e] << 15) | (u32)bf16rne(eval[e]);
      const int p = atomicAdd(&cnt[r >> 6], 1);
      p64[p] = ((u64)(r & (RPB - 1)) << 32) | (u64)lo;
    }
  }
}

// ------- FUSED sort-by-(row,colgroup) + column-phase-sweep aggregation -----
// Block = 512 threads = 8 waves = one 64-row bucket; wave owns 8 rows.
// Sort key = row_low*16 + col/8192 (13 groups). Aggregation loops groups
// OUTER: the whole GPU gathers from one 2.1MB column slice per phase.
__global__ __launch_bounds__(512) void agg_sort_kernel(
    const ushort* __restrict__ Xh,
    const int* __restrict__ bbase, const u64* __restrict__ p64,
    ushort* __restrict__ Yh) {
  __shared__ u32 sbuf[CAP3];
  __shared__ int hist[RPB * NGRP];     // 1024
  __shared__ int rstart[RPB * NGRP];
  __shared__ int curs[RPB * NGRP];
  __shared__ int wsum[16];
  const int b = blockIdx.x, t = threadIdx.x;
  const int lane = t & 63, wid = t >> 6;
  const int s = bbase[b];
  int nE = bbase[b + 1] - s;
  if (nE > CAP3) nE = CAP3;            // never expected (+14 sigma)

  hist[t] = 0; hist[t + 512] = 0;
  __syncthreads();
  for (int i = t; i < nE; i += 512) {
    const u64 w = p64[s + i];
    const int key = (((int)(w >> 32) & 63) << 4) | (int)((u32)w >> 28);
    atomicAdd(&hist[key], 1);
  }
  __syncthreads();
  // scan 1024 counters (2 per thread)
  int v0 = hist[t], v1 = hist[t + 512];
  int i0 = v0, i1 = v1;
  #pragma unroll
  for (int off = 1; off < 64; off <<= 1) {
    int n0 = __shfl_up(i0, off, 64);
    int n1 = __shfl_up(i1, off, 64);
    if (lane >= off) { i0 += n0; i1 += n1; }
  }
  if (lane == 63) { wsum[wid] = i0; wsum[8 + wid] = i1; }
  __syncthreads();
  if (t == 0) {
    int sa = 0;
    #pragma unroll
    for (int k = 0; k < 16; ++k) { int x = wsum[k]; wsum[k] = sa; sa += x; }
  }
  __syncthreads();
  const int ex0 = wsum[wid] + i0 - v0;
  const int ex1 = wsum[8 + wid] + i1 - v1;
  rstart[t] = ex0; curs[t] = ex0;
  rstart[t + 512] = ex1; curs[t + 512] = ex1;
  __syncthreads();
  for (int i = t; i < nE; i += 512) {
    const u64 w = p64[s + i];                    // L2-hot second read
    const int key = (((int)(w >> 32) & 63) << 4) | (int)((u32)w >> 28);
    sbuf[atomicAdd(&curs[key], 1)] = (u32)w;
  }
  __syncthreads();

  // ---- aggregation: group-outer sweep, 8 rows/wave, quarter-wave gathers --
  const int q = lane >> 4;
  const u32 sub16 = (u32)(lane & 15) * 16u;
  const char* Xb = (const char*)Xh;
  const int rbase = wid * 8;
  float f[8][8];
  #pragma unroll
  for (int j = 0; j < 8; ++j)
    #pragma unroll
    for (int k = 0; k < 8; ++k) f[j][k] = 0.f;

  #pragma unroll 1
  for (int g = 0; g < 13; ++g) {
    #pragma unroll
    for (int j = 0; j < 8; ++j) {
      const int key = ((rbase + j) << 4) | g;
      const int s0 = rstart[key];
      const int s1 = s0 + hist[key];
      for (int e = s0 + q; e < s1; e += 4) {
        const u32 lo = sbuf[e];
        const uint4 gq = *(const uint4*)(Xb + (((lo >> 7) & 0xFFFFFF00u) + sub16));
        const float v = __uint_as_float((lo & 0x7fffu) << 16);
        f[j][0] += v * lofl(gq.x); f[j][1] += v * hifl(gq.x);
        f[j][2] += v * lofl(gq.y); f[j][3] += v * hifl(gq.y);
        f[j][4] += v * lofl(gq.z); f[j][5] += v * hifl(gq.z);
        f[j][6] += v * lofl(gq.w); f[j][7] += v * hifl(gq.w);
      }
    }
  }

  #pragma unroll
  for (int j = 0; j < 8; ++j) {
    #pragma unroll
    for (int k = 0; k < 8; ++k) {
      f[j][k] += __shfl_xor(f[j][k], 16);
      f[j][k] += __shfl_xor(f[j][k], 32);
    }
    const int gr = b * RPB + rbase + j;
    if (gr < N_NODES && lane < 16) {
      uint4 o;
      o.x = (u32)bf16rne(f[j][0]) | ((u32)bf16rne(f[j][1]) << 16);
      o.y = (u32)bf16rne(f[j][2]) | ((u32)bf16rne(f[j][3]) << 16);
      o.z = (u32)bf16rne(f[j][4]) | ((u32)bf16rne(f[j][5]) << 16);
      o.w = (u32)bf16rne(f[j][6]) | ((u32)bf16rne(f[j][7]) << 16);
      ((uint4*)(Yh + (size_t)gr * DIM))[lane] = o;
    }
  }
}

// ------- MFMA GEMM: out = Yh @ Wh + bias (256 rows/block, B amortized) -----
__global__ __launch_bounds__(256) void gemm_mfma(const ushort* __restrict__ Yh,
                                                 const ushort* __restrict__ Wh,
                                                 const float* __restrict__ bias,
                                                 float* __restrict__ out) {
  const int wid = threadIdx.x >> 6, lane = threadIdx.x & 63;
  const int lr = lane & 15, lq = lane >> 4;
  const int n0 = wid * 32;

  bf16x8 bfrag[4][2];
  float bval[2];
  #pragma unroll
  for (int nt = 0; nt < 2; ++nt) {
    const int col = n0 + nt * 16 + lr;
    bval[nt] = bias[col];
    #pragma unroll
    for (int kk = 0; kk < 4; ++kk) {
      const int kbase = kk * 32 + lq * 8;
      bf16x8 b;
      #pragma unroll
      for (int i = 0; i < 8; ++i)
        b[i] = (short)Wh[(size_t)(kbase + i) * DIM + col];
      bfrag[kk][nt] = b;
    }
  }

  const int r0 = blockIdx.x * 256;
  #pragma unroll 1
  for (int g = 0; g < 16; ++g) {
    const int m0 = r0 + g * 16;
    if (m0 >= N_NODES) break;
    bf16x8 afrag[4];
    const ushort* arow = Yh + (size_t)(m0 + lr) * DIM + lq * 8;
    #pragma unroll
    for (int kk = 0; kk < 4; ++kk)
      afrag[kk] = *(const bf16x8*)(arow + kk * 32);
    #pragma unroll
    for (int nt = 0; nt < 2; ++nt) {
      f32x4 acc = {0.f, 0.f, 0.f, 0.f};
      #pragma unroll
      for (int kk = 0; kk < 4; ++kk)
        acc = __builtin_amdgcn_mfma_f32_16x16x32_bf16(afrag[kk], bfrag[kk][nt], acc, 0, 0, 0);
      const int col = n0 + nt * 16 + lr;
      #pragma unroll
      for (int j = 0; j < 4; ++j)
        out[(size_t)(m0 + lq * 4 + j) * DIM + col] = acc[j] + bval[nt];
    }
  }
}

// ------- fallback path (small ws) ------------------------------------------
__global__ __launch_bounds__(128) void gemm_kernel(
    const float* __restrict__ IN, const float* __restrict__ W,
    float* __restrict__ OUT, const float* __restrict__ bias, int add_bias) {
  __shared__ float Wsh[DIM * DIM];
  __shared__ float Xsh[RB * DIM];
  const int t = threadIdx.x;
  #pragma unroll 8
  for (int i = 0; i < DIM; ++i) Wsh[i * DIM + t] = W[i * DIM + t];
  const int r0 = blockIdx.x * RB;
  #pragma unroll
  for (int idx = t; idx < RB * DIM; idx += 128)
    Xsh[idx] = IN[(size_t)r0 * DIM + idx];
  __syncthreads();
  float acc[RB];
  const float b = add_bias ? bias[t] : 0.f;
  #pragma unroll
  for (int r = 0; r < RB; ++r) acc[r] = b;
  for (int k = 0; k < DIM; ++k) {
    const float w = Wsh[k * DIM + t];
    #pragma unroll
    for (int r = 0; r < RB; ++r) acc[r] += Xsh[r * DIM + k] * w;
  }
  #pragma unroll
  for (int r = 0; r < RB; ++r)
    OUT[(size_t)(r0 + r) * DIM + t] = acc[r];
}

__global__ void init_kernel(float* __restrict__ out, const float* __restrict__ bias) {
  const size_t total4 = (size_t)N_NODES * DIM / 4;
  const float4* b4 = (const float4*)bias;
  float4* o4 = (float4*)out;
  for (size_t i = (size_t)blockIdx.x * blockDim.x + threadIdx.x;
       i < total4; i += (size_t)gridDim.x * blockDim.x)
    o4[i] = b4[i & 31];
}

__global__ __launch_bounds__(256) void scatter_kernel(
    const float* __restrict__ S,
    const int* __restrict__ erow, const int* __restrict__ ecol,
    const float* __restrict__ eval, float* __restrict__ out) {
  const long long g = (long long)blockIdx.x * blockDim.x + threadIdx.x;
  const long long e = g >> 5;
  const int lane = (int)(g & 31);
  if (e >= N_EDGES) return;
  const int r = erow[e];
  const int c = ecol[e];
  const float v = eval[e];
  const float4 x = ((const float4*)(S + (size_t)c * DIM))[lane];
  float* o = out + (size_t)r * DIM + lane * 4;
  atomicAdd(o + 0, v * x.x);
  atomicAdd(o + 1, v * x.y);
  atomicAdd(o + 2, v * x.z);
  atomicAdd(o + 3, v * x.w);
}

extern "C" void kernel_launch(void* const* d_in, const int* in_sizes, int n_in,
                              void* d_out, int out_size, void* d_ws, size_t ws_size,
                              hipStream_t stream) {
  const float* X    = (const float*)d_in[0];
  const int*   erow = (const int*)d_in[1];
  const int*   ecol = (const int*)d_in[2];
  const float* eval = (const float*)d_in[3];
  const float* W    = (const float*)d_in[4];
  const float* bias = (const float*)d_in[5];
  float* out = (float*)d_out;

  const size_t P64_BYTES = (size_t)N_EDGES * 8;          // 25.6 MB
  const size_t XH_BYTES  = (size_t)N_NODES * DIM * 2;    // 25.6 MB
  const size_t YH_BYTES  = (size_t)N_NODES * DIM * 2;    // 25.6 MB (aliases table)
  const size_t WH_BYTES  = (size_t)DIM * DIM * 2;        // 32 KB
  const size_t BB_BYTES  = (size_t)(NBKT + 1) * 4;
  const size_t BC_BYTES  = (size_t)NBKT * 4;
  const size_t NEED = P64_BYTES + XH_BYTES + YH_BYTES + WH_BYTES +
                      BB_BYTES + BC_BYTES + 256;

  if (ws_size >= NEED) {
    char* w = (char*)d_ws;
    u64*    p64     = (u64*)w;     w += P64_BYTES;
    ushort* Xh      = (ushort*)w;  w += XH_BYTES;
    ushort* Yh      = (ushort*)w;  w += YH_BYTES;
    ushort* Wh      = (ushort*)w;  w += WH_BYTES;
    int*    bbase   = (int*)w;     w += BB_BYTES;
    int*    bcur    = (int*)w;     // counts, then cursors
    int*    table   = (int*)Yh;    // NCHK*NBKT ints = 2.44 MB, lifetime-disjoint

    hipMemsetAsync(bcur, 0, BC_BYTES, stream);
    prep_count_kernel<<<1024 + NCHK, 256, 0, stream>>>(X, W, Xh, Wh, erow, bcur, table);
    bscan_kernel<<<1, 1024, 0, stream>>>(bcur, bbase);
    partition_kernel<<<NCHK, 256, 0, stream>>>(erow, ecol, eval, table, bcur, p64);
    agg_sort_kernel<<<NBKT, 512, 0, stream>>>(Xh, bbase, p64, Yh);
    gemm_mfma<<<(N_NODES + 255) / 256, 256, 0, stream>>>(Yh, Wh, bias, out);
  } else {
    float* S = (float*)d_ws;
    init_kernel<<<2048, 256, 0, stream>>>(out, bias);
    gemm_kernel<<<N_NODES / RB, 128, 0, stream>>>(X, W, S, bias, 0);
    const long long threads = (long long)N_EDGES * 32;
    scatter_kernel<<<(int)((threads + 255) / 256), 256, 0, stream>>>(S, erow, ecol, eval, out);
  }
}

// Round 12
// 232.384 us; speedup vs baseline: 1.3983x; 1.3983x over previous
//
#include <hip/hip_runtime.h>
#include <hip/hip_bf16.h>

// GraphConv: out = segment_sum(edge_val * X[edge_col], edge_row) @ W + bias
// Pipeline: prep(bf16 X,W)+bucket-count(+table) | bucket-scan | partition
// (u64{row_low|col|val} into 1563 64-row buckets) | FUSED per-bucket LDS
// counting sort (row key) + quarter-wave uint4 gather aggregation
// (256-thread blocks -> 8 resident/CU) | MFMA GEMM (+bias)

#define N_NODES 100000
#define N_EDGES 3200000
#define DIM 128
#define RB 16
#define RPB 64                                   // rows per bucket
#define NBKT ((N_NODES + RPB - 1) / RPB)         // 1563
#define CHUNK 8192
#define NCHK ((N_EDGES + CHUNK - 1) / CHUNK)     // 391
#define CAP3 2688                                // bucket cap (mean 2047, +14 sigma)

typedef __attribute__((ext_vector_type(8))) short bf16x8;
typedef __attribute__((ext_vector_type(4))) float f32x4;
typedef unsigned long long u64;
typedef unsigned int u32;

__device__ inline ushort bf16rne(float f) {
  uint32_t u = __float_as_uint(f);
  u += 0x7fffu + ((u >> 16) & 1u);
  return (ushort)(u >> 16);
}
__device__ inline float lofl(u32 u) { return __uint_as_float(u << 16); }
__device__ inline float hifl(u32 u) { return __uint_as_float(u & 0xffff0000u); }

// ------- fused: prep (blocks 0..1023) + bucket count (blocks 1024..) -------
__global__ __launch_bounds__(256) void prep_count_kernel(
    const float* __restrict__ X, const float* __restrict__ W,
    ushort* __restrict__ Xh, ushort* __restrict__ Wh,
    const int* __restrict__ erow, int* __restrict__ bcnt,
    int* __restrict__ table) {
  __shared__ int cnt[NBKT];
  if (blockIdx.x < 1024) {
    const size_t nx4 = (size_t)N_NODES * DIM / 4;
    const size_t nw4 = (size_t)DIM * DIM / 4;
    for (size_t i = (size_t)blockIdx.x * blockDim.x + threadIdx.x;
         i < nx4 + nw4; i += (size_t)1024 * blockDim.x) {
      const float4 f = (i < nx4) ? ((const float4*)X)[i] : ((const float4*)W)[i - nx4];
      ushort4 h;
      h.x = bf16rne(f.x); h.y = bf16rne(f.y); h.z = bf16rne(f.z); h.w = bf16rne(f.w);
      if (i < nx4) ((ushort4*)Xh)[i] = h;
      else         ((ushort4*)Wh)[i - nx4] = h;
    }
  } else {
    const int cb = blockIdx.x - 1024;
    for (int b = threadIdx.x; b < NBKT; b += 256) cnt[b] = 0;
    __syncthreads();
    const int e0 = cb * CHUNK;
    #pragma unroll
    for (int it = 0; it < CHUNK / 256; ++it) {
      const int e = e0 + it * 256 + threadIdx.x;
      if (e < N_EDGES) atomicAdd(&cnt[erow[e] >> 6], 1);
    }
    __syncthreads();
    for (int b = threadIdx.x; b < NBKT; b += 256) {
      const int c = cnt[b];
      table[(size_t)cb * NBKT + b] = c;
      if (c) atomicAdd(&bcnt[b], c);
    }
  }
}

// ------- exclusive scan over 1563 bucket counts (2 elems/thread) -----------
__global__ __launch_bounds__(1024) void bscan_kernel(int* __restrict__ bcur,
                                                     int* __restrict__ bbase) {
  __shared__ int wsum[32];
  const int t = threadIdx.x, lane = t & 63, wid = t >> 6;   // wid 0..15
  int v0 = (t < NBKT) ? bcur[t] : 0;
  int v1 = (t + 1024 < NBKT) ? bcur[t + 1024] : 0;
  int i0 = v0, i1 = v1;
  #pragma unroll
  for (int off = 1; off < 64; off <<= 1) {
    int n0 = __shfl_up(i0, off, 64);
    int n1 = __shfl_up(i1, off, 64);
    if (lane >= off) { i0 += n0; i1 += n1; }
  }
  if (lane == 63) { wsum[wid] = i0; wsum[16 + wid] = i1; }
  __syncthreads();
  if (t == 0) {
    int s = 0;
    #pragma unroll
    for (int k = 0; k < 32; ++k) { int x = wsum[k]; wsum[k] = s; s += x; }
    bbase[NBKT] = s;
  }
  __syncthreads();
  const int e0 = wsum[wid] + i0 - v0;
  const int e1 = wsum[16 + wid] + i1 - v1;
  if (t < NBKT) { bbase[t] = e0; bcur[t] = e0; }
  if (t + 1024 < NBKT) { bbase[t + 1024] = e1; bcur[t + 1024] = e1; }
}

// ------- partition edges into buckets (u64 = row_low | col | val) ----------
__global__ __launch_bounds__(256) void partition_kernel(
    const int* __restrict__ erow, const int* __restrict__ ecol,
    const float* __restrict__ eval, const int* __restrict__ table,
    int* __restrict__ bcur, u64* __restrict__ p64) {
  __shared__ int cnt[NBKT];
  const int e0 = blockIdx.x * CHUNK;
  for (int b = threadIdx.x; b < NBKT; b += 256) {
    const int c = table[(size_t)blockIdx.x * NBKT + b];
    cnt[b] = c ? atomicAdd(&bcur[b], c) : 0;
  }
  __syncthreads();
  #pragma unroll
  for (int it = 0; it < CHUNK / 256; ++it) {
    const int e = e0 + it * 256 + threadIdx.x;
    if (e < N_EDGES) {
      const int r = erow[e];
      const u32 lo = ((u32)ecol[e] << 15) | (u32)bf16rne(eval[e]);
      const int p = atomicAdd(&cnt[r >> 6], 1);
      p64[p] = ((u64)(r & (RPB - 1)) << 32) | (u64)lo;
    }
  }
}

// ------- FUSED per-bucket sort + aggregation (256 threads, 64-row bucket) --
// 4 waves; wave owns 16 rows. Single-wave scan of the 64 row counters.
__global__ __launch_bounds__(256) void agg_sort_kernel(
    const ushort* __restrict__ Xh,
    const int* __restrict__ bbase, const u64* __restrict__ p64,
    ushort* __restrict__ Yh) {
  __shared__ u32 sbuf[CAP3];
  __shared__ int hist[RPB];
  __shared__ int rstart[RPB];
  __shared__ int curs[RPB];
  const int b = blockIdx.x, t = threadIdx.x;
  const int s = bbase[b];
  int nE = bbase[b + 1] - s;
  if (nE > CAP3) nE = CAP3;            // never expected (+14 sigma)

  if (t < RPB) hist[t] = 0;
  __syncthreads();
  for (int i = t; i < nE; i += 256)
    atomicAdd(&hist[(int)(p64[s + i] >> 32) & (RPB - 1)], 1);
  __syncthreads();
  if (t < RPB) {                        // t<64 == wave 0: single-wave scan
    const int v = hist[t];
    int incl = v;
    #pragma unroll
    for (int off = 1; off < 64; off <<= 1) {
      int n = __shfl_up(incl, off, 64);
      if (t >= off) incl += n;
    }
    rstart[t] = incl - v;
    curs[t] = incl - v;
  }
  __syncthreads();
  for (int i = t; i < nE; i += 256) {
    const u64 w = p64[s + i];                    // L2-hot second read
    const int p = atomicAdd(&curs[(int)(w >> 32) & (RPB - 1)], 1);
    sbuf[p] = (u32)w;
  }
  __syncthreads();

  // ---- aggregation: wave wid handles rows [wid*16, wid*16+16) ----
  const int wid = t >> 6, lane = t & 63;
  const int q = lane >> 4;                 // quarter 0..3
  const u32 sub16 = (u32)(lane & 15) * 16u;
  const char* Xb = (const char*)Xh;
  #pragma unroll 1
  for (int j = 0; j < 16; ++j) {
    const int rl = wid * 16 + j;           // row within bucket
    const int gr = b * RPB + rl;
    const int s0 = rstart[rl];
    const int s1 = s0 + hist[rl];
    float f0 = 0.f, f1 = 0.f, f2 = 0.f, f3 = 0.f;
    float f4 = 0.f, f5 = 0.f, f6 = 0.f, f7 = 0.f;
    #pragma unroll 1
    for (int e = s0 + q; e < s1; e += 16) {
      const u32 lo0 = sbuf[e];
      const u32 lo1 = (e + 4  < s1) ? sbuf[e + 4]  : 0u;
      const u32 lo2 = (e + 8  < s1) ? sbuf[e + 8]  : 0u;
      const u32 lo3 = (e + 12 < s1) ? sbuf[e + 12] : 0u;
      const u32 o0 = (lo0 >> 7) & 0xFFFFFF00u;   // col*256 byte offset
      const u32 o1 = (lo1 >> 7) & 0xFFFFFF00u;
      const u32 o2 = (lo2 >> 7) & 0xFFFFFF00u;
      const u32 o3 = (lo3 >> 7) & 0xFFFFFF00u;
      const uint4 g0 = *(const uint4*)(Xb + (o0 + sub16));
      const uint4 g1 = *(const uint4*)(Xb + (o1 + sub16));
      const uint4 g2 = *(const uint4*)(Xb + (o2 + sub16));
      const uint4 g3 = *(const uint4*)(Xb + (o3 + sub16));
      const float v0 = __uint_as_float((lo0 & 0x7fffu) << 16);
      const float v1 = __uint_as_float((lo1 & 0x7fffu) << 16);
      const float v2 = __uint_as_float((lo2 & 0x7fffu) << 16);
      const float v3 = __uint_as_float((lo3 & 0x7fffu) << 16);
      f0 += v0 * lofl(g0.x); f1 += v0 * hifl(g0.x);
      f2 += v0 * lofl(g0.y); f3 += v0 * hifl(g0.y);
      f4 += v0 * lofl(g0.z); f5 += v0 * hifl(g0.z);
      f6 += v0 * lofl(g0.w); f7 += v0 * hifl(g0.w);
      f0 += v1 * lofl(g1.x); f1 += v1 * hifl(g1.x);
      f2 += v1 * lofl(g1.y); f3 += v1 * hifl(g1.y);
      f4 += v1 * lofl(g1.z); f5 += v1 * hifl(g1.z);
      f6 += v1 * lofl(g1.w); f7 += v1 * hifl(g1.w);
      f0 += v2 * lofl(g2.x); f1 += v2 * hifl(g2.x);
      f2 += v2 * lofl(g2.y); f3 += v2 * hifl(g2.y);
      f4 += v2 * lofl(g2.z); f5 += v2 * hifl(g2.z);
      f6 += v2 * lofl(g2.w); f7 += v2 * hifl(g2.w);
      f0 += v3 * lofl(g3.x); f1 += v3 * hifl(g3.x);
      f2 += v3 * lofl(g3.y); f3 += v3 * hifl(g3.y);
      f4 += v3 * lofl(g3.z); f5 += v3 * hifl(g3.z);
      f6 += v3 * lofl(g3.w); f7 += v3 * hifl(g3.w);
    }
    f0 += __shfl_xor(f0, 16); f1 += __shfl_xor(f1, 16);
    f2 += __shfl_xor(f2, 16); f3 += __shfl_xor(f3, 16);
    f4 += __shfl_xor(f4, 16); f5 += __shfl_xor(f5, 16);
    f6 += __shfl_xor(f6, 16); f7 += __shfl_xor(f7, 16);
    f0 += __shfl_xor(f0, 32); f1 += __shfl_xor(f1, 32);
    f2 += __shfl_xor(f2, 32); f3 += __shfl_xor(f3, 32);
    f4 += __shfl_xor(f4, 32); f5 += __shfl_xor(f5, 32);
    f6 += __shfl_xor(f6, 32); f7 += __shfl_xor(f7, 32);
    if (gr < N_NODES && lane < 16) {
      uint4 o;
      o.x = (u32)bf16rne(f0) | ((u32)bf16rne(f1) << 16);
      o.y = (u32)bf16rne(f2) | ((u32)bf16rne(f3) << 16);
      o.z = (u32)bf16rne(f4) | ((u32)bf16rne(f5) << 16);
      o.w = (u32)bf16rne(f6) | ((u32)bf16rne(f7) << 16);
      ((uint4*)(Yh + (size_t)gr * DIM))[lane] = o;
    }
  }
}

// ------- MFMA GEMM: out = Yh @ Wh + bias (256 rows/block, B amortized) -----
__global__ __launch_bounds__(256) void gemm_mfma(const ushort* __restrict__ Yh,
                                                 const ushort* __restrict__ Wh,
                                                 const float* __restrict__ bias,
                                                 float* __restrict__ out) {
  const int wid = threadIdx.x >> 6, lane = threadIdx.x & 63;
  const int lr = lane & 15, lq = lane >> 4;
  const int n0 = wid * 32;

  bf16x8 bfrag[4][2];
  float bval[2];
  #pragma unroll
  for (int nt = 0; nt < 2; ++nt) {
    const int col = n0 + nt * 16 + lr;
    bval[nt] = bias[col];
    #pragma unroll
    for (int kk = 0; kk < 4; ++kk) {
      const int kbase = kk * 32 + lq * 8;
      bf16x8 b;
      #pragma unroll
      for (int i = 0; i < 8; ++i)
        b[i] = (short)Wh[(size_t)(kbase + i) * DIM + col];
      bfrag[kk][nt] = b;
    }
  }

  const int r0 = blockIdx.x * 256;
  #pragma unroll 1
  for (int g = 0; g < 16; ++g) {
    const int m0 = r0 + g * 16;
    if (m0 >= N_NODES) break;
    bf16x8 afrag[4];
    const ushort* arow = Yh + (size_t)(m0 + lr) * DIM + lq * 8;
    #pragma unroll
    for (int kk = 0; kk < 4; ++kk)
      afrag[kk] = *(const bf16x8*)(arow + kk * 32);
    #pragma unroll
    for (int nt = 0; nt < 2; ++nt) {
      f32x4 acc = {0.f, 0.f, 0.f, 0.f};
      #pragma unroll
      for (int kk = 0; kk < 4; ++kk)
        acc = __builtin_amdgcn_mfma_f32_16x16x32_bf16(afrag[kk], bfrag[kk][nt], acc, 0, 0, 0);
      const int col = n0 + nt * 16 + lr;
      #pragma unroll
      for (int j = 0; j < 4; ++j)
        out[(size_t)(m0 + lq * 4 + j) * DIM + col] = acc[j] + bval[nt];
    }
  }
}

// ------- fallback path (small ws) ------------------------------------------
__global__ __launch_bounds__(128) void gemm_kernel(
    const float* __restrict__ IN, const float* __restrict__ W,
    float* __restrict__ OUT, const float* __restrict__ bias, int add_bias) {
  __shared__ float Wsh[DIM * DIM];
  __shared__ float Xsh[RB * DIM];
  const int t = threadIdx.x;
  #pragma unroll 8
  for (int i = 0; i < DIM; ++i) Wsh[i * DIM + t] = W[i * DIM + t];
  const int r0 = blockIdx.x * RB;
  #pragma unroll
  for (int idx = t; idx < RB * DIM; idx += 128)
    Xsh[idx] = IN[(size_t)r0 * DIM + idx];
  __syncthreads();
  float acc[RB];
  const float b = add_bias ? bias[t] : 0.f;
  #pragma unroll
  for (int r = 0; r < RB; ++r) acc[r] = b;
  for (int k = 0; k < DIM; ++k) {
    const float w = Wsh[k * DIM + t];
    #pragma unroll
    for (int r = 0; r < RB; ++r) acc[r] += Xsh[r * DIM + k] * w;
  }
  #pragma unroll
  for (int r = 0; r < RB; ++r)
    OUT[(size_t)(r0 + r) * DIM + t] = acc[r];
}

__global__ void init_kernel(float* __restrict__ out, const float* __restrict__ bias) {
  const size_t total4 = (size_t)N_NODES * DIM / 4;
  const float4* b4 = (const float4*)bias;
  float4* o4 = (float4*)out;
  for (size_t i = (size_t)blockIdx.x * blockDim.x + threadIdx.x;
       i < total4; i += (size_t)gridDim.x * blockDim.x)
    o4[i] = b4[i & 31];
}

__global__ __launch_bounds__(256) void scatter_kernel(
    const float* __restrict__ S,
    const int* __restrict__ erow, const int* __restrict__ ecol,
    const float* __restrict__ eval, float* __restrict__ out) {
  const long long g = (long long)blockIdx.x * blockDim.x + threadIdx.x;
  const long long e = g >> 5;
  const int lane = (int)(g & 31);
  if (e >= N_EDGES) return;
  const int r = erow[e];
  const int c = ecol[e];
  const float v = eval[e];
  const float4 x = ((const float4*)(S + (size_t)c * DIM))[lane];
  float* o = out + (size_t)r * DIM + lane * 4;
  atomicAdd(o + 0, v * x.x);
  atomicAdd(o + 1, v * x.y);
  atomicAdd(o + 2, v * x.z);
  atomicAdd(o + 3, v * x.w);
}

extern "C" void kernel_launch(void* const* d_in, const int* in_sizes, int n_in,
                              void* d_out, int out_size, void* d_ws, size_t ws_size,
                              hipStream_t stream) {
  const float* X    = (const float*)d_in[0];
  const int*   erow = (const int*)d_in[1];
  const int*   ecol = (const int*)d_in[2];
  const float* eval = (const float*)d_in[3];
  const float* W    = (const float*)d_in[4];
  const float* bias = (const float*)d_in[5];
  float* out = (float*)d_out;

  const size_t P64_BYTES = (size_t)N_EDGES * 8;          // 25.6 MB
  const size_t XH_BYTES  = (size_t)N_NODES * DIM * 2;    // 25.6 MB
  const size_t YH_BYTES  = (size_t)N_NODES * DIM * 2;    // 25.6 MB (aliases table)
  const size_t WH_BYTES  = (size_t)DIM * DIM * 2;        // 32 KB
  const size_t BB_BYTES  = (size_t)(NBKT + 1) * 4;
  const size_t BC_BYTES  = (size_t)NBKT * 4;
  const size_t NEED = P64_BYTES + XH_BYTES + YH_BYTES + WH_BYTES +
                      BB_BYTES + BC_BYTES + 256;

  if (ws_size >= NEED) {
    char* w = (char*)d_ws;
    u64*    p64     = (u64*)w;     w += P64_BYTES;
    ushort* Xh      = (ushort*)w;  w += XH_BYTES;
    ushort* Yh      = (ushort*)w;  w += YH_BYTES;
    ushort* Wh      = (ushort*)w;  w += WH_BYTES;
    int*    bbase   = (int*)w;     w += BB_BYTES;
    int*    bcur    = (int*)w;     // counts, then cursors
    int*    table   = (int*)Yh;    // NCHK*NBKT ints = 2.44 MB, lifetime-disjoint

    hipMemsetAsync(bcur, 0, BC_BYTES, stream);
    prep_count_kernel<<<1024 + NCHK, 256, 0, stream>>>(X, W, Xh, Wh, erow, bcur, table);
    bscan_kernel<<<1, 1024, 0, stream>>>(bcur, bbase);
    partition_kernel<<<NCHK, 256, 0, stream>>>(erow, ecol, eval, table, bcur, p64);
    agg_sort_kernel<<<NBKT, 256, 0, stream>>>(Xh, bbase, p64, Yh);
    gemm_mfma<<<(N_NODES + 255) / 256, 256, 0, stream>>>(Yh, Wh, bias, out);
  } else {
    float* S = (float*)d_ws;
    init_kernel<<<2048, 256, 0, stream>>>(out, bias);
    gemm_kernel<<<N_NODES / RB, 128, 0, stream>>>(X, W, S, bias, 0);
    const long long threads = (long long)N_EDGES * 32;
    scatter_kernel<<<(int)((threads + 255) / 256), 256, 0, stream>>>(S, erow, ecol, eval, out);
  }
}

// Round 13
// 210.931 us; speedup vs baseline: 1.5406x; 1.1017x over previous
//
#include <hip/hip_runtime.h>
#include <hip/hip_bf16.h>

// GraphConv: out = segment_sum(edge_val * X[edge_col], edge_row) @ W + bias
// Pipeline: prep(bf16 X, W^T)+per-chunk bucket count table | cscan (table ->
// per-(bucket,chunk) exclusive offsets, NO global atomics) | bscan | partition
// (pure-read cursor bases, u64{row_low|col|val} into 1563 64-row buckets) |
// FUSED per-bucket LDS counting sort + quarter-wave uint4 gather agg |
// MFMA GEMM (vectorized B-frags from W^T, +bias)

#define N_NODES 100000
#define N_EDGES 3200000
#define DIM 128
#define RB 16
#define RPB 64                                   // rows per bucket
#define NBKT ((N_NODES + RPB - 1) / RPB)         // 1563
#define CHUNK 8192
#define NCHK ((N_EDGES + CHUNK - 1) / CHUNK)     // 391
#define CAP3 2688                                // bucket cap (mean 2047, +14 sigma)

typedef __attribute__((ext_vector_type(8))) short bf16x8;
typedef __attribute__((ext_vector_type(4))) float f32x4;
typedef unsigned long long u64;
typedef unsigned int u32;

__device__ inline ushort bf16rne(float f) {
  uint32_t u = __float_as_uint(f);
  u += 0x7fffu + ((u >> 16) & 1u);
  return (ushort)(u >> 16);
}
__device__ inline float lofl(u32 u) { return __uint_as_float(u << 16); }
__device__ inline float hifl(u32 u) { return __uint_as_float(u & 0xffff0000u); }

// ------- fused: prep (blocks 0..1023) + per-chunk bucket count -------------
// table[cb*NBKT + b] = count of chunk cb's edges in bucket b (no atomics).
__global__ __launch_bounds__(256) void prep_count_kernel(
    const float* __restrict__ X, const float* __restrict__ W,
    ushort* __restrict__ Xh, ushort* __restrict__ WhT,
    const int* __restrict__ erow, int* __restrict__ table) {
  __shared__ int cnt[NBKT];
  if (blockIdx.x < 1024) {
    const size_t nx4 = (size_t)N_NODES * DIM / 4;
    const size_t nw4 = (size_t)DIM * DIM / 4;
    for (size_t i = (size_t)blockIdx.x * blockDim.x + threadIdx.x;
         i < nx4 + nw4; i += (size_t)1024 * blockDim.x) {
      if (i < nx4) {
        const float4 f = ((const float4*)X)[i];
        ushort4 h;
        h.x = bf16rne(f.x); h.y = bf16rne(f.y); h.z = bf16rne(f.z); h.w = bf16rne(f.w);
        ((ushort4*)Xh)[i] = h;
      } else {
        const float4 f = ((const float4*)W)[i - nx4];
        const int elem = (int)(i - nx4) * 4;       // k*DIM + col
        const int k = elem >> 7, col = elem & 127;
        WhT[(size_t)(col + 0) * DIM + k] = bf16rne(f.x);   // W^T[col][k]
        WhT[(size_t)(col + 1) * DIM + k] = bf16rne(f.y);
        WhT[(size_t)(col + 2) * DIM + k] = bf16rne(f.z);
        WhT[(size_t)(col + 3) * DIM + k] = bf16rne(f.w);
      }
    }
  } else {
    const int cb = blockIdx.x - 1024;
    for (int b = threadIdx.x; b < NBKT; b += 256) cnt[b] = 0;
    __syncthreads();
    const int e0 = cb * CHUNK;
    #pragma unroll
    for (int it = 0; it < CHUNK / 256; ++it) {
      const int e = e0 + it * 256 + threadIdx.x;
      if (e < N_EDGES) atomicAdd(&cnt[erow[e] >> 6], 1);
    }
    __syncthreads();
    for (int b = threadIdx.x; b < NBKT; b += 256)
      table[(size_t)cb * NBKT + b] = cnt[b];       // coalesced, no atomics
  }
}

// ------- cscan: per-bucket exclusive scan over 391 chunk counts ------------
// In-place: table[cb][b] becomes offset of chunk cb within bucket b.
// bcnt[b] = bucket total. Wave per bucket; lanes stride over chunks.
__global__ __launch_bounds__(256) void cscan_kernel(int* __restrict__ table,
                                                    int* __restrict__ bcnt) {
  const int b = blockIdx.x * 4 + (threadIdx.x >> 6);
  if (b >= NBKT) return;
  const int lane = threadIdx.x & 63;
  int carry = 0;
  #pragma unroll
  for (int r = 0; r < (NCHK + 63) / 64; ++r) {
    const int cb = r * 64 + lane;
    const int c = (cb < NCHK) ? table[(size_t)cb * NBKT + b] : 0;
    int incl = c;
    #pragma unroll
    for (int off = 1; off < 64; off <<= 1) {
      int n = __shfl_up(incl, off, 64);
      if (lane >= off) incl += n;
    }
    if (cb < NCHK) table[(size_t)cb * NBKT + b] = carry + incl - c;
    carry += __shfl(incl, 63, 64);
  }
  if (lane == 0) bcnt[b] = carry;
}

// ------- exclusive scan over 1563 bucket totals -> bbase -------------------
__global__ __launch_bounds__(1024) void bscan_kernel(const int* __restrict__ bcnt,
                                                     int* __restrict__ bbase) {
  __shared__ int wsum[32];
  const int t = threadIdx.x, lane = t & 63, wid = t >> 6;   // wid 0..15
  int v0 = (t < NBKT) ? bcnt[t] : 0;
  int v1 = (t + 1024 < NBKT) ? bcnt[t + 1024] : 0;
  int i0 = v0, i1 = v1;
  #pragma unroll
  for (int off = 1; off < 64; off <<= 1) {
    int n0 = __shfl_up(i0, off, 64);
    int n1 = __shfl_up(i1, off, 64);
    if (lane >= off) { i0 += n0; i1 += n1; }
  }
  if (lane == 63) { wsum[wid] = i0; wsum[16 + wid] = i1; }
  __syncthreads();
  if (t == 0) {
    int s = 0;
    #pragma unroll
    for (int k = 0; k < 32; ++k) { int x = wsum[k]; wsum[k] = s; s += x; }
    bbase[NBKT] = s;
  }
  __syncthreads();
  if (t < NBKT) bbase[t] = wsum[wid] + i0 - v0;
  if (t + 1024 < NBKT) bbase[t + 1024] = wsum[16 + wid] + i1 - v1;
}

// ------- partition edges into buckets (pure-read cursor bases) -------------
__global__ __launch_bounds__(256) void partition_kernel(
    const int* __restrict__ erow, const int* __restrict__ ecol,
    const float* __restrict__ eval, const int* __restrict__ table,
    const int* __restrict__ bbase, u64* __restrict__ p64) {
  __shared__ int cnt[NBKT];
  const int e0 = blockIdx.x * CHUNK;
  for (int b = threadIdx.x; b < NBKT; b += 256)
    cnt[b] = bbase[b] + table[(size_t)blockIdx.x * NBKT + b];  // coalesced
  __syncthreads();
  #pragma unroll
  for (int it = 0; it < CHUNK / 256; ++it) {
    const int e = e0 + it * 256 + threadIdx.x;
    if (e < N_EDGES) {
      const int r = erow[e];
      const u32 lo = ((u32)ecol[e] << 15) | (u32)bf16rne(eval[e]);
      const int p = atomicAdd(&cnt[r >> 6], 1);     // LDS atomic only
      p64[p] = ((u64)(r & (RPB - 1)) << 32) | (u64)lo;
    }
  }
}

// ------- FUSED per-bucket sort + aggregation (256 threads, 64-row bucket) --
__global__ __launch_bounds__(256) void agg_sort_kernel(
    const ushort* __restrict__ Xh,
    const int* __restrict__ bbase, const u64* __restrict__ p64,
    ushort* __restrict__ Yh) {
  __shared__ u32 sbuf[CAP3];
  __shared__ int hist[RPB];
  __shared__ int rstart[RPB];
  __shared__ int curs[RPB];
  const int b = blockIdx.x, t = threadIdx.x;
  const int s = bbase[b];
  int nE = bbase[b + 1] - s;
  if (nE > CAP3) nE = CAP3;            // never expected (+14 sigma)

  if (t < RPB) hist[t] = 0;
  __syncthreads();
  for (int i = t; i < nE; i += 256)
    atomicAdd(&hist[(int)(p64[s + i] >> 32) & (RPB - 1)], 1);
  __syncthreads();
  if (t < RPB) {                        // t<64 == wave 0: single-wave scan
    const int v = hist[t];
    int incl = v;
    #pragma unroll
    for (int off = 1; off < 64; off <<= 1) {
      int n = __shfl_up(incl, off, 64);
      if (t >= off) incl += n;
    }
    rstart[t] = incl - v;
    curs[t] = incl - v;
  }
  __syncthreads();
  for (int i = t; i < nE; i += 256) {
    const u64 w = p64[s + i];                    // L2-hot second read
    const int p = atomicAdd(&curs[(int)(w >> 32) & (RPB - 1)], 1);
    sbuf[p] = (u32)w;
  }
  __syncthreads();

  // ---- aggregation: wave wid handles rows [wid*16, wid*16+16) ----
  const int wid = t >> 6, lane = t & 63;
  const int q = lane >> 4;                 // quarter 0..3
  const u32 sub16 = (u32)(lane & 15) * 16u;
  const char* Xb = (const char*)Xh;
  #pragma unroll 1
  for (int j = 0; j < 16; ++j) {
    const int rl = wid * 16 + j;           // row within bucket
    const int gr = b * RPB + rl;
    const int s0 = rstart[rl];
    const int s1 = s0 + hist[rl];
    float f0 = 0.f, f1 = 0.f, f2 = 0.f, f3 = 0.f;
    float f4 = 0.f, f5 = 0.f, f6 = 0.f, f7 = 0.f;
    #pragma unroll 1
    for (int e = s0 + q; e < s1; e += 16) {
      const u32 lo0 = sbuf[e];
      const u32 lo1 = (e + 4  < s1) ? sbuf[e + 4]  : 0u;
      const u32 lo2 = (e + 8  < s1) ? sbuf[e + 8]  : 0u;
      const u32 lo3 = (e + 12 < s1) ? sbuf[e + 12] : 0u;
      const u32 o0 = (lo0 >> 7) & 0xFFFFFF00u;   // col*256 byte offset
      const u32 o1 = (lo1 >> 7) & 0xFFFFFF00u;
      const u32 o2 = (lo2 >> 7) & 0xFFFFFF00u;
      const u32 o3 = (lo3 >> 7) & 0xFFFFFF00u;
      const uint4 g0 = *(const uint4*)(Xb + (o0 + sub16));
      const uint4 g1 = *(const uint4*)(Xb + (o1 + sub16));
      const uint4 g2 = *(const uint4*)(Xb + (o2 + sub16));
      const uint4 g3 = *(const uint4*)(Xb + (o3 + sub16));
      const float v0 = __uint_as_float((lo0 & 0x7fffu) << 16);
      const float v1 = __uint_as_float((lo1 & 0x7fffu) << 16);
      const float v2 = __uint_as_float((lo2 & 0x7fffu) << 16);
      const float v3 = __uint_as_float((lo3 & 0x7fffu) << 16);
      f0 += v0 * lofl(g0.x); f1 += v0 * hifl(g0.x);
      f2 += v0 * lofl(g0.y); f3 += v0 * hifl(g0.y);
      f4 += v0 * lofl(g0.z); f5 += v0 * hifl(g0.z);
      f6 += v0 * lofl(g0.w); f7 += v0 * hifl(g0.w);
      f0 += v1 * lofl(g1.x); f1 += v1 * hifl(g1.x);
      f2 += v1 * lofl(g1.y); f3 += v1 * hifl(g1.y);
      f4 += v1 * lofl(g1.z); f5 += v1 * hifl(g1.z);
      f6 += v1 * lofl(g1.w); f7 += v1 * hifl(g1.w);
      f0 += v2 * lofl(g2.x); f1 += v2 * hifl(g2.x);
      f2 += v2 * lofl(g2.y); f3 += v2 * hifl(g2.y);
      f4 += v2 * lofl(g2.z); f5 += v2 * hifl(g2.z);
      f6 += v2 * lofl(g2.w); f7 += v2 * hifl(g2.w);
      f0 += v3 * lofl(g3.x); f1 += v3 * hifl(g3.x);
      f2 += v3 * lofl(g3.y); f3 += v3 * hifl(g3.y);
      f4 += v3 * lofl(g3.z); f5 += v3 * hifl(g3.z);
      f6 += v3 * lofl(g3.w); f7 += v3 * hifl(g3.w);
    }
    f0 += __shfl_xor(f0, 16); f1 += __shfl_xor(f1, 16);
    f2 += __shfl_xor(f2, 16); f3 += __shfl_xor(f3, 16);
    f4 += __shfl_xor(f4, 16); f5 += __shfl_xor(f5, 16);
    f6 += __shfl_xor(f6, 16); f7 += __shfl_xor(f7, 16);
    f0 += __shfl_xor(f0, 32); f1 += __shfl_xor(f1, 32);
    f2 += __shfl_xor(f2, 32); f3 += __shfl_xor(f3, 32);
    f4 += __shfl_xor(f4, 32); f5 += __shfl_xor(f5, 32);
    f6 += __shfl_xor(f6, 32); f7 += __shfl_xor(f7, 32);
    if (gr < N_NODES && lane < 16) {
      uint4 o;
      o.x = (u32)bf16rne(f0) | ((u32)bf16rne(f1) << 16);
      o.y = (u32)bf16rne(f2) | ((u32)bf16rne(f3) << 16);
      o.z = (u32)bf16rne(f4) | ((u32)bf16rne(f5) << 16);
      o.w = (u32)bf16rne(f6) | ((u32)bf16rne(f7) << 16);
      ((uint4*)(Yh + (size_t)gr * DIM))[lane] = o;
    }
  }
}

// ------- MFMA GEMM: out = Yh @ W + bias (B-frags vector-loaded from W^T) ---
__global__ __launch_bounds__(256) void gemm_mfma(const ushort* __restrict__ Yh,
                                                 const ushort* __restrict__ WhT,
                                                 const float* __restrict__ bias,
                                                 float* __restrict__ out) {
  const int wid = threadIdx.x >> 6, lane = threadIdx.x & 63;
  const int lr = lane & 15, lq = lane >> 4;
  const int n0 = wid * 32;

  bf16x8 bfrag[4][2];
  float bval[2];
  #pragma unroll
  for (int nt = 0; nt < 2; ++nt) {
    const int col = n0 + nt * 16 + lr;
    bval[nt] = bias[col];
    #pragma unroll
    for (int kk = 0; kk < 4; ++kk)
      bfrag[kk][nt] = *(const bf16x8*)(WhT + (size_t)col * DIM + kk * 32 + lq * 8);
  }

  const int r0 = blockIdx.x * 256;
  #pragma unroll 1
  for (int g = 0; g < 16; ++g) {
    const int m0 = r0 + g * 16;
    if (m0 >= N_NODES) break;
    bf16x8 afrag[4];
    const ushort* arow = Yh + (size_t)(m0 + lr) * DIM + lq * 8;
    #pragma unroll
    for (int kk = 0; kk < 4; ++kk)
      afrag[kk] = *(const bf16x8*)(arow + kk * 32);
    #pragma unroll
    for (int nt = 0; nt < 2; ++nt) {
      f32x4 acc = {0.f, 0.f, 0.f, 0.f};
      #pragma unroll
      for (int kk = 0; kk < 4; ++kk)
        acc = __builtin_amdgcn_mfma_f32_16x16x32_bf16(afrag[kk], bfrag[kk][nt], acc, 0, 0, 0);
      const int col = n0 + nt * 16 + lr;
      #pragma unroll
      for (int j = 0; j < 4; ++j)
        out[(size_t)(m0 + lq * 4 + j) * DIM + col] = acc[j] + bval[nt];
    }
  }
}

// ------- fallback path (small ws) ------------------------------------------
__global__ __launch_bounds__(128) void gemm_kernel(
    const float* __restrict__ IN, const float* __restrict__ W,
    float* __restrict__ OUT, const float* __restrict__ bias, int add_bias) {
  __shared__ float Wsh[DIM * DIM];
  __shared__ float Xsh[RB * DIM];
  const int t = threadIdx.x;
  #pragma unroll 8
  for (int i = 0; i < DIM; ++i) Wsh[i * DIM + t] = W[i * DIM + t];
  const int r0 = blockIdx.x * RB;
  #pragma unroll
  for (int idx = t; idx < RB * DIM; idx += 128)
    Xsh[idx] = IN[(size_t)r0 * DIM + idx];
  __syncthreads();
  float acc[RB];
  const float b = add_bias ? bias[t] : 0.f;
  #pragma unroll
  for (int r = 0; r < RB; ++r) acc[r] = b;
  for (int k = 0; k < DIM; ++k) {
    const float w = Wsh[k * DIM + t];
    #pragma unroll
    for (int r = 0; r < RB; ++r) acc[r] += Xsh[r * DIM + k] * w;
  }
  #pragma unroll
  for (int r = 0; r < RB; ++r)
    OUT[(size_t)(r0 + r) * DIM + t] = acc[r];
}

__global__ void init_kernel(float* __restrict__ out, const float* __restrict__ bias) {
  const size_t total4 = (size_t)N_NODES * DIM / 4;
  const float4* b4 = (const float4*)bias;
  float4* o4 = (float4*)out;
  for (size_t i = (size_t)blockIdx.x * blockDim.x + threadIdx.x;
       i < total4; i += (size_t)gridDim.x * blockDim.x)
    o4[i] = b4[i & 31];
}

__global__ __launch_bounds__(256) void scatter_kernel(
    const float* __restrict__ S,
    const int* __restrict__ erow, const int* __restrict__ ecol,
    const float* __restrict__ eval, float* __restrict__ out) {
  const long long g = (long long)blockIdx.x * blockDim.x + threadIdx.x;
  const long long e = g >> 5;
  const int lane = (int)(g & 31);
  if (e >= N_EDGES) return;
  const int r = erow[e];
  const int c = ecol[e];
  const float v = eval[e];
  const float4 x = ((const float4*)(S + (size_t)c * DIM))[lane];
  float* o = out + (size_t)r * DIM + lane * 4;
  atomicAdd(o + 0, v * x.x);
  atomicAdd(o + 1, v * x.y);
  atomicAdd(o + 2, v * x.z);
  atomicAdd(o + 3, v * x.w);
}

extern "C" void kernel_launch(void* const* d_in, const int* in_sizes, int n_in,
                              void* d_out, int out_size, void* d_ws, size_t ws_size,
                              hipStream_t stream) {
  const float* X    = (const float*)d_in[0];
  const int*   erow = (const int*)d_in[1];
  const int*   ecol = (const int*)d_in[2];
  const float* eval = (const float*)d_in[3];
  const float* W    = (const float*)d_in[4];
  const float* bias = (const float*)d_in[5];
  float* out = (float*)d_out;

  const size_t P64_BYTES = (size_t)N_EDGES * 8;          // 25.6 MB
  const size_t XH_BYTES  = (size_t)N_NODES * DIM * 2;    // 25.6 MB
  const size_t YH_BYTES  = (size_t)N_NODES * DIM * 2;    // 25.6 MB (aliases table)
  const size_t WHT_BYTES = (size_t)DIM * DIM * 2;        // 32 KB
  const size_t BB_BYTES  = (size_t)(NBKT + 1) * 4;
  const size_t BC_BYTES  = (size_t)NBKT * 4;
  const size_t NEED = P64_BYTES + XH_BYTES + YH_BYTES + WHT_BYTES +
                      BB_BYTES + BC_BYTES + 256;

  if (ws_size >= NEED) {
    char* w = (char*)d_ws;
    u64*    p64     = (u64*)w;     w += P64_BYTES;
    ushort* Xh      = (ushort*)w;  w += XH_BYTES;
    ushort* Yh      = (ushort*)w;  w += YH_BYTES;
    ushort* WhT     = (ushort*)w;  w += WHT_BYTES;
    int*    bbase   = (int*)w;     w += BB_BYTES;
    int*    bcnt    = (int*)w;     w += BC_BYTES;
    int*    table   = (int*)Yh;    // NCHK*NBKT ints = 2.44 MB, lifetime-disjoint

    prep_count_kernel<<<1024 + NCHK, 256, 0, stream>>>(X, W, Xh, WhT, erow, table);
    cscan_kernel<<<(NBKT + 3) / 4, 256, 0, stream>>>(table, bcnt);
    bscan_kernel<<<1, 1024, 0, stream>>>(bcnt, bbase);
    partition_kernel<<<NCHK, 256, 0, stream>>>(erow, ecol, eval, table, bbase, p64);
    agg_sort_kernel<<<NBKT, 256, 0, stream>>>(Xh, bbase, p64, Yh);
    gemm_mfma<<<(N_NODES + 255) / 256, 256, 0, stream>>>(Yh, WhT, bias, out);
  } else {
    float* S = (float*)d_ws;
    init_kernel<<<2048, 256, 0, stream>>>(out, bias);
    gemm_kernel<<<N_NODES / RB, 128, 0, stream>>>(X, W, S, bias, 0);
    const long long threads = (long long)N_EDGES * 32;
    scatter_kernel<<<(int)((threads + 255) / 256), 256, 0, stream>>>(S, erow, ecol, eval, out);
  }
}